// Round 3
// baseline (161.488 us; speedup 1.0000x reference)
//
#include <hip/hip_runtime.h>
#include <math.h>

#define BATCH 8192
#define DIM 1024
#define NCLS 1000
#define NPAD 1024         // padded class rows for the bf16 center matrix
#define NPAIRS 499500.0f  // 1000*999/2

typedef float  f32x4  __attribute__((ext_vector_type(4)));
typedef short  bf16x8 __attribute__((ext_vector_type(8)));

// ---------------- helpers ----------------

__device__ inline float waveAllReduceAdd(float x) {
  #pragma unroll
  for (int m = 32; m > 0; m >>= 1) x += __shfl_xor(x, m);
  return x;
}

// block (256 thr) reduce, broadcast; sm >= 8 floats
__device__ inline float blockReduce1(float x, float* sm) {
  x = waveAllReduceAdd(x);
  int lane = threadIdx.x & 63, wid = threadIdx.x >> 6;
  __syncthreads();
  if (lane == 0) sm[wid] = x;
  __syncthreads();
  return sm[0] + sm[1] + sm[2] + sm[3];
}

__device__ inline float2 blockReduce2(float x, float y, float* sm) {
  x = waveAllReduceAdd(x);
  y = waveAllReduceAdd(y);
  int lane = threadIdx.x & 63, wid = threadIdx.x >> 6;
  __syncthreads();
  if (lane == 0) { sm[wid * 2] = x; sm[wid * 2 + 1] = y; }
  __syncthreads();
  return make_float2(sm[0] + sm[2] + sm[4] + sm[6], sm[1] + sm[3] + sm[5] + sm[7]);
}

__device__ inline float bf2f(unsigned short u) {
  return __uint_as_float(((unsigned int)u) << 16);
}

__device__ inline unsigned short f2bf(float f) {
  unsigned int u = __float_as_uint(f);
  u += 0x7FFFu + ((u >> 16) & 1u);  // RNE
  return (unsigned short)(u >> 16);
}

// ---------------- K1: wave-per-row inv L2 norms of clean features ----------------

__global__ void norms_kernel(const float* __restrict__ feats, float* __restrict__ invn) {
  int lane = threadIdx.x & 63;
  int row = blockIdx.x * 4 + (threadIdx.x >> 6);
  const float4* f4 = (const float4*)(feats + (size_t)row * DIM);
  float ss = 0.f;
  #pragma unroll
  for (int i = 0; i < 4; ++i) {
    float4 v = f4[lane + 64 * i];
    ss += v.x * v.x + v.y * v.y + v.z * v.z + v.w * v.w;
  }
  ss = waveAllReduceAdd(ss);
  if (lane == 0) invn[row] = 1.0f / fmaxf(sqrtf(ss), 1e-12f);
}

// ---------------- K2: single-block histogram + exclusive scan + zero partials ----

__global__ void hist_scan_kernel(const int* __restrict__ labels, int* counts,
                                 int* offsets, int* cursor, float* partials) {
  __shared__ int h[1024];
  int t = threadIdx.x;  // 1024 threads, 1 block
  h[t] = 0;
  if (t < 768) partials[t] = 0.0f;
  __syncthreads();
  #pragma unroll
  for (int j = t; j < BATCH; j += 1024) atomicAdd(&h[labels[j]], 1);
  __syncthreads();
  int v = h[t];
  if (t < NCLS) counts[t] = v;
  for (int off = 1; off < 1024; off <<= 1) {
    int u = (t >= off) ? h[t - off] : 0;
    __syncthreads();
    h[t] += u;
    __syncthreads();
  }
  if (t < NCLS) {
    int e = h[t] - v;  // exclusive prefix
    offsets[t] = e;
    cursor[t] = e;
  }
}

// ---------------- K3: counting-sort scatter ----------------

__global__ void scatter_kernel(const int* __restrict__ labels, int* cursor,
                               int* rows_sorted) {
  int j = blockIdx.x * 256 + threadIdx.x;
  if (j < BATCH) {
    int pos = atomicAdd(&cursor[labels[j]], 1);
    rows_sorted[pos] = j;
  }
}

// ---------------- K4: fused center update + both intra losses ----------------
// One 256-thread block per padded class row. Pass 1: masked mean of normalized
// clean rows. Then momentum update, bf16 store, ||c||^2. Pass 2: re-walk the
// same rows (feats now L2-hot), read adv rows, compute per-row
// ||f_n - c|| and ||fa_n - c|| contributions.

__global__ void update_intra_kernel(const float* __restrict__ feats,
                                    const float* __restrict__ featsa,
                                    const float* __restrict__ centers,
                                    const int* __restrict__ counts,
                                    const int* __restrict__ offsets,
                                    const int* __restrict__ rows_sorted,
                                    const float* __restrict__ invn,
                                    unsigned short* __restrict__ centers_bf,
                                    float* __restrict__ sqn,
                                    float* __restrict__ partials) {
  __shared__ float sm[8];
  __shared__ int s_anynz;
  int c = blockIdx.x;   // 0..1023
  int tid = threadIdx.x;

  if (c >= NCLS) {  // zero-pad rows so the MFMA kernel can load unguarded
    ((ushort4*)(centers_bf + (size_t)c * DIM))[tid] = make_ushort4(0, 0, 0, 0);
    return;
  }

  int n = counts[c];
  int off = offsets[c];

  // pass 1: mean of normalized clean rows
  float4 acc = make_float4(0.f, 0.f, 0.f, 0.f);
  for (int t = 0; t < n; ++t) {
    int r = rows_sorted[off + t];
    float w = invn[r];
    float4 v = ((const float4*)(feats + (size_t)r * DIM))[tid];
    acc.x += v.x * w; acc.y += v.y * w; acc.z += v.z * w; acc.w += v.w * w;
  }
  float invc = 1.0f / fmaxf((float)n, 1.0f);
  float4 mean = make_float4(acc.x * invc, acc.y * invc, acc.z * invc, acc.w * invc);

  float4 cv = ((const float4*)(centers + (size_t)c * DIM))[tid];
  if (tid == 0) s_anynz = 0;
  __syncthreads();
  if (cv.x != 0.f || cv.y != 0.f || cv.z != 0.f || cv.w != 0.f) s_anynz = 1;
  __syncthreads();

  float4 o;
  if (s_anynz) {
    o = make_float4(0.9f * cv.x + 0.1f * mean.x, 0.9f * cv.y + 0.1f * mean.y,
                    0.9f * cv.z + 0.1f * mean.z, 0.9f * cv.w + 0.1f * mean.w);
  } else {
    o = mean;
  }
  if (n == 0) o = cv;

  ((ushort4*)(centers_bf + (size_t)c * DIM))[tid] =
      make_ushort4(f2bf(o.x), f2bf(o.y), f2bf(o.z), f2bf(o.w));

  float sq = blockReduce1(o.x * o.x + o.y * o.y + o.z * o.z + o.w * o.w, sm);
  if (tid == 0) sqn[c] = sq;

  // pass 2: intra contributions for this class's rows
  float accC = 0.f, accA = 0.f;
  for (int t = 0; t < n; ++t) {
    int r = rows_sorted[off + t];
    float4 f = ((const float4*)(feats + (size_t)r * DIM))[tid];   // L2-hot
    float4 fa = ((const float4*)(featsa + (size_t)r * DIM))[tid];
    float ssa = blockReduce1(
        fa.x * fa.x + fa.y * fa.y + fa.z * fa.z + fa.w * fa.w, sm);
    float inva = 1.0f / fmaxf(sqrtf(ssa), 1e-12f);
    float invf = invn[r];
    float dx = f.x * invf - o.x, dy = f.y * invf - o.y;
    float dz = f.z * invf - o.z, dw = f.w * invf - o.w;
    float ex = fa.x * inva - o.x, ey = fa.y * inva - o.y;
    float ez = fa.z * inva - o.z, ew = fa.w * inva - o.w;
    float2 d2 = blockReduce2(dx * dx + dy * dy + dz * dz + dw * dw,
                             ex * ex + ey * ey + ez * ez + ew * ew, sm);
    if (tid == 0) { accC += sqrtf(d2.x); accA += sqrtf(d2.y); }
  }
  if (tid == 0 && n > 0) {
    int slot = c & 255;
    atomicAdd(&partials[slot], accC);
    atomicAdd(&partials[256 + slot], accA);
  }
}

// ---------------- K5: inter loss, bf16 MFMA Gram, 64x64 tile per block -------
// wave w of 4 computes the 32x32 quadrant (wy=w>>1, wx=w&1) as 2x2 MFMA
// 16x16x32 fragments. A[m=lane&15][k=(lane>>4)*8+j]; C/D: col=lane&15,
// row=(lane>>4)*4+reg (verified layouts).

__global__ void inter_mfma_kernel(const unsigned short* __restrict__ Cbf,
                                  const float* __restrict__ sq,
                                  float* __restrict__ inter_partial) {
  int bi = blockIdx.y, bj = blockIdx.x;
  if (bj < bi) return;  // upper triangle of tiles

  __shared__ float smr[8];
  int tid = threadIdx.x;          // 256
  int w = tid >> 6;
  int wy = w >> 1, wx = w & 1;
  int lane = tid & 63;
  int m = lane & 15;
  int q = lane >> 4;

  int i0 = bi * 64 + wy * 32;
  int j0 = bj * 64 + wx * 32;

  const unsigned short* arow0 = Cbf + (size_t)(i0 + m) * DIM;
  const unsigned short* arow1 = Cbf + (size_t)(i0 + 16 + m) * DIM;
  const unsigned short* brow0 = Cbf + (size_t)(j0 + m) * DIM;
  const unsigned short* brow1 = Cbf + (size_t)(j0 + 16 + m) * DIM;

  f32x4 acc00 = {0.f, 0.f, 0.f, 0.f}, acc01 = acc00, acc10 = acc00, acc11 = acc00;

  #pragma unroll 4
  for (int k0 = 0; k0 < DIM; k0 += 32) {
    int ko = k0 + q * 8;
    bf16x8 a0 = *(const bf16x8*)(arow0 + ko);
    bf16x8 a1 = *(const bf16x8*)(arow1 + ko);
    bf16x8 b0 = *(const bf16x8*)(brow0 + ko);
    bf16x8 b1 = *(const bf16x8*)(brow1 + ko);
    acc00 = __builtin_amdgcn_mfma_f32_16x16x32_bf16(a0, b0, acc00, 0, 0, 0);
    acc01 = __builtin_amdgcn_mfma_f32_16x16x32_bf16(a0, b1, acc01, 0, 0, 0);
    acc10 = __builtin_amdgcn_mfma_f32_16x16x32_bf16(a1, b0, acc10, 0, 0, 0);
    acc11 = __builtin_amdgcn_mfma_f32_16x16x32_bf16(a1, b1, acc11, 0, 0, 0);
  }

  float local = 0.f;
  int colA = lane & 15;
  int rbase = (lane >> 4) * 4;
  #pragma unroll
  for (int si = 0; si < 2; ++si) {
    #pragma unroll
    for (int sj = 0; sj < 2; ++sj) {
      f32x4 a = (si == 0) ? (sj == 0 ? acc00 : acc01) : (sj == 0 ? acc10 : acc11);
      #pragma unroll
      for (int r = 0; r < 4; ++r) {
        int i = i0 + si * 16 + rbase + r;
        int j = j0 + sj * 16 + colA;
        if (j < NCLS && i < j) {
          float d2 = sq[i] + sq[j] - 2.0f * a[r];
          float d = sqrtf(fmaxf(d2, 0.0f));
          local += fmaxf(1.0f - d, 0.0f);
        }
      }
    }
  }
  float tot = blockReduce1(local, smr);
  if (tid == 0) atomicAdd(&inter_partial[(bi * 16 + bj) & 255], tot);
}

// ---------------- K6: final combine ----------------

__global__ void final_kernel(const float* __restrict__ partials, float* __restrict__ out) {
  __shared__ float sm[8];
  int t = threadIdx.x;  // 256
  float c = partials[t] + partials[256 + t];
  float e = partials[512 + t];
  c = blockReduce1(c, sm);
  e = blockReduce1(e, sm);
  if (t == 0) {
    float intra = c * (1.0f / (float)BATCH);
    float inter = e / NPAIRS;
    out[0] = intra - 0.5f * inter;  // LAMBDA_INTRA=1, LAMBDA_INTER=0.5
  }
}

// ---------------- launch ----------------

extern "C" void kernel_launch(void* const* d_in, const int* in_sizes, int n_in,
                              void* d_out, int out_size, void* d_ws, size_t ws_size,
                              hipStream_t stream) {
  const float* features     = (const float*)d_in[0];
  const float* features_adv = (const float*)d_in[1];
  const float* centers      = (const float*)d_in[2];
  const int*   labels       = (const int*)d_in[3];
  float* out = (float*)d_out;

  // ws layout: centers_bf[1024*1024 u16] | sqn[1000 f] | invn[8192 f] |
  //            partials[768 f] | counts/offsets/cursor[1000 i each] | rows_sorted[8192 i]
  unsigned short* centers_bf = (unsigned short*)d_ws;
  float* sqn = (float*)(centers_bf + (size_t)NPAD * DIM);
  float* invn = sqn + NCLS;
  float* partials = invn + BATCH;
  int* counts = (int*)(partials + 768);
  int* offsets = counts + NCLS;
  int* cursor = offsets + NCLS;
  int* rows_sorted = cursor + NCLS;

  hipLaunchKernelGGL(norms_kernel, dim3(BATCH / 4), dim3(256), 0, stream,
                     features, invn);
  hipLaunchKernelGGL(hist_scan_kernel, dim3(1), dim3(1024), 0, stream, labels,
                     counts, offsets, cursor, partials);
  hipLaunchKernelGGL(scatter_kernel, dim3(BATCH / 256), dim3(256), 0, stream, labels,
                     cursor, rows_sorted);
  hipLaunchKernelGGL(update_intra_kernel, dim3(NPAD), dim3(256), 0, stream, features,
                     features_adv, centers, counts, offsets, rows_sorted, invn,
                     centers_bf, sqn, partials);
  hipLaunchKernelGGL(inter_mfma_kernel, dim3(16, 16), dim3(256), 0, stream, centers_bf,
                     sqn, partials + 512);
  hipLaunchKernelGGL(final_kernel, dim3(1), dim3(256), 0, stream, partials, out);
}

// Round 4
// 155.078 us; speedup vs baseline: 1.0413x; 1.0413x over previous
//
#include <hip/hip_runtime.h>
#include <math.h>

#define BATCH 8192
#define DIM 1024
#define NCLS 1000
#define NPAD 1024         // padded class rows for the bf16 center matrix
#define NPAIRS 499500.0f  // 1000*999/2

typedef float  f32x4  __attribute__((ext_vector_type(4)));
typedef short  bf16x8 __attribute__((ext_vector_type(8)));

// ---------------- helpers ----------------

__device__ inline float waveAllReduceAdd(float x) {
  #pragma unroll
  for (int m = 32; m > 0; m >>= 1) x += __shfl_xor(x, m);
  return x;
}

// block (256 thr) reduce, broadcast; sm >= 8 floats
__device__ inline float blockReduce1(float x, float* sm) {
  x = waveAllReduceAdd(x);
  int lane = threadIdx.x & 63, wid = threadIdx.x >> 6;
  __syncthreads();
  if (lane == 0) sm[wid] = x;
  __syncthreads();
  return sm[0] + sm[1] + sm[2] + sm[3];
}

__device__ inline unsigned short f2bf(float f) {
  unsigned int u = __float_as_uint(f);
  u += 0x7FFFu + ((u >> 16) & 1u);  // RNE
  return (unsigned short)(u >> 16);
}

// ---------------- K1: wave-per-row inv L2 norms of clean features ------------

__global__ void norms_kernel(const float* __restrict__ feats, float* __restrict__ invn) {
  int lane = threadIdx.x & 63;
  int row = blockIdx.x * 4 + (threadIdx.x >> 6);
  const float4* f4 = (const float4*)(feats + (size_t)row * DIM);
  float ss = 0.f;
  #pragma unroll
  for (int i = 0; i < 4; ++i) {
    float4 v = f4[lane + 64 * i];
    ss += v.x * v.x + v.y * v.y + v.z * v.z + v.w * v.w;
  }
  ss = waveAllReduceAdd(ss);
  if (lane == 0) invn[row] = 1.0f / fmaxf(sqrtf(ss), 1e-12f);
}

// ---------------- K2: 1-block histogram + scan + LDS-cursor scatter ----------

__global__ void hist_scan_scatter_kernel(const int* __restrict__ labels, int* counts,
                                         int* offsets, int* rows_sorted,
                                         float* partials) {
  __shared__ int h[1024];
  __shared__ int cur[1024];
  int t = threadIdx.x;  // 1024 threads, 1 block
  h[t] = 0;
  if (t < 768) partials[t] = 0.0f;
  __syncthreads();
  #pragma unroll
  for (int j = t; j < BATCH; j += 1024) atomicAdd(&h[labels[j]], 1);
  __syncthreads();
  int v = h[t];
  if (t < NCLS) counts[t] = v;
  for (int off = 1; off < 1024; off <<= 1) {
    int u = (t >= off) ? h[t - off] : 0;
    __syncthreads();
    h[t] += u;
    __syncthreads();
  }
  int e = h[t] - v;  // exclusive prefix
  cur[t] = e;
  if (t < NCLS) offsets[t] = e;
  __syncthreads();
  #pragma unroll
  for (int j = t; j < BATCH; j += 1024) {
    int pos = atomicAdd(&cur[labels[j]], 1);
    rows_sorted[pos] = j;
  }
}

// ---------------- K3: center update, wave-per-DIM-segment --------------------
// Block = 256 thr = 4 waves; wave w owns columns [w*256, w*256+256). Each wave
// independently accumulates its segment over the class's rows (no barriers in
// the loop), applies momentum, stores bf16, then one block-reduce for ||c||^2.

__global__ void update_centers_kernel(const float* __restrict__ feats,
                                      const float* __restrict__ centers,
                                      const int* __restrict__ counts,
                                      const int* __restrict__ offsets,
                                      const int* __restrict__ rows_sorted,
                                      const float* __restrict__ invn,
                                      unsigned short* __restrict__ centers_bf,
                                      float* __restrict__ sqn) {
  __shared__ float sm[8];
  __shared__ int s_anynz;
  int c = blockIdx.x;   // 0..1023
  int tid = threadIdx.x;
  int fi = tid;         // float4 index within the 256-float4 row (wave w -> fi in [64w,64w+64))

  if (c >= NCLS) {  // zero-pad rows so the MFMA kernel can load unguarded
    ((ushort4*)(centers_bf + (size_t)c * DIM))[fi] = make_ushort4(0, 0, 0, 0);
    return;
  }

  int n = counts[c];
  int off = offsets[c];

  float4 acc = make_float4(0.f, 0.f, 0.f, 0.f);
  for (int t = 0; t < n; ++t) {
    int r = rows_sorted[off + t];
    float w = invn[r];
    float4 v = ((const float4*)(feats + (size_t)r * DIM))[fi];
    acc.x += v.x * w; acc.y += v.y * w; acc.z += v.z * w; acc.w += v.w * w;
  }
  float invc = 1.0f / fmaxf((float)n, 1.0f);
  float4 mean = make_float4(acc.x * invc, acc.y * invc, acc.z * invc, acc.w * invc);

  float4 cv = ((const float4*)(centers + (size_t)c * DIM))[fi];
  if (tid == 0) s_anynz = 0;
  __syncthreads();
  if (cv.x != 0.f || cv.y != 0.f || cv.z != 0.f || cv.w != 0.f) s_anynz = 1;
  __syncthreads();

  float4 o;
  if (s_anynz) {
    o = make_float4(0.9f * cv.x + 0.1f * mean.x, 0.9f * cv.y + 0.1f * mean.y,
                    0.9f * cv.z + 0.1f * mean.z, 0.9f * cv.w + 0.1f * mean.w);
  } else {
    o = mean;
  }
  if (n == 0) o = cv;

  ((ushort4*)(centers_bf + (size_t)c * DIM))[fi] =
      make_ushort4(f2bf(o.x), f2bf(o.y), f2bf(o.z), f2bf(o.w));

  float sq = blockReduce1(o.x * o.x + o.y * o.y + o.z * o.z + o.w * o.w, sm);
  if (tid == 0) sqn[c] = sq;
}

// ---------------- K4: intra losses, wave-per-row, barrier-free ---------------

__global__ void intra_kernel(const float* __restrict__ feats,
                             const float* __restrict__ featsa,
                             const unsigned short* __restrict__ centers_bf,
                             const int* __restrict__ labels,
                             const float* __restrict__ invn,
                             float* __restrict__ partials) {
  int lane = threadIdx.x & 63;
  int row = blockIdx.x * 4 + (threadIdx.x >> 6);
  const float4* f4 = (const float4*)(feats + (size_t)row * DIM);
  const float4* a4 = (const float4*)(featsa + (size_t)row * DIM);
  int lab = labels[row];
  const ushort4* c4 = (const ushort4*)(centers_bf + (size_t)lab * DIM);

  float4 fv[4], av[4];
  ushort4 cv[4];
  float ssa = 0.f;
  #pragma unroll
  for (int i = 0; i < 4; ++i) {
    fv[i] = f4[lane + 64 * i];
    av[i] = a4[lane + 64 * i];
    cv[i] = c4[lane + 64 * i];
    ssa += av[i].x * av[i].x + av[i].y * av[i].y + av[i].z * av[i].z + av[i].w * av[i].w;
  }
  ssa = waveAllReduceAdd(ssa);
  float inva = 1.0f / fmaxf(sqrtf(ssa), 1e-12f);
  float invf = invn[row];

  float d2c = 0.f, d2a = 0.f;
  #pragma unroll
  for (int i = 0; i < 4; ++i) {
    float cx = __uint_as_float((unsigned)cv[i].x << 16);
    float cy = __uint_as_float((unsigned)cv[i].y << 16);
    float cz = __uint_as_float((unsigned)cv[i].z << 16);
    float cw = __uint_as_float((unsigned)cv[i].w << 16);
    float dx = fv[i].x * invf - cx, dy = fv[i].y * invf - cy;
    float dz = fv[i].z * invf - cz, dw = fv[i].w * invf - cw;
    d2c += dx * dx + dy * dy + dz * dz + dw * dw;
    float ex = av[i].x * inva - cx, ey = av[i].y * inva - cy;
    float ez = av[i].z * inva - cz, ew = av[i].w * inva - cw;
    d2a += ex * ex + ey * ey + ez * ez + ew * ew;
  }
  d2c = waveAllReduceAdd(d2c);
  d2a = waveAllReduceAdd(d2a);
  if (lane == 0) {
    int slot = row & 255;
    atomicAdd(&partials[slot], sqrtf(d2c));
    atomicAdd(&partials[256 + slot], sqrtf(d2a));
  }
}

// ---------------- K5: inter loss, bf16 MFMA Gram, 64x64 tile per block -------
// wave w of 4: quadrant (wy=w>>1, wx=w&1) as 2x2 mfma_f32_16x16x32_bf16.
// A[m=lane&15][k=(lane>>4)*8+j]; C/D: col=lane&15, row=(lane>>4)*4+reg.

__global__ void inter_mfma_kernel(const unsigned short* __restrict__ Cbf,
                                  const float* __restrict__ sq,
                                  float* __restrict__ inter_partial) {
  int bi = blockIdx.y, bj = blockIdx.x;
  if (bj < bi) return;  // upper triangle of tiles

  __shared__ float smr[8];
  int tid = threadIdx.x;          // 256
  int w = tid >> 6;
  int wy = w >> 1, wx = w & 1;
  int lane = tid & 63;
  int m = lane & 15;
  int q = lane >> 4;

  int i0 = bi * 64 + wy * 32;
  int j0 = bj * 64 + wx * 32;

  const unsigned short* arow0 = Cbf + (size_t)(i0 + m) * DIM;
  const unsigned short* arow1 = Cbf + (size_t)(i0 + 16 + m) * DIM;
  const unsigned short* brow0 = Cbf + (size_t)(j0 + m) * DIM;
  const unsigned short* brow1 = Cbf + (size_t)(j0 + 16 + m) * DIM;

  f32x4 acc00 = {0.f, 0.f, 0.f, 0.f}, acc01 = acc00, acc10 = acc00, acc11 = acc00;

  #pragma unroll 4
  for (int k0 = 0; k0 < DIM; k0 += 32) {
    int ko = k0 + q * 8;
    bf16x8 a0 = *(const bf16x8*)(arow0 + ko);
    bf16x8 a1 = *(const bf16x8*)(arow1 + ko);
    bf16x8 b0 = *(const bf16x8*)(brow0 + ko);
    bf16x8 b1 = *(const bf16x8*)(brow1 + ko);
    acc00 = __builtin_amdgcn_mfma_f32_16x16x32_bf16(a0, b0, acc00, 0, 0, 0);
    acc01 = __builtin_amdgcn_mfma_f32_16x16x32_bf16(a0, b1, acc01, 0, 0, 0);
    acc10 = __builtin_amdgcn_mfma_f32_16x16x32_bf16(a1, b0, acc10, 0, 0, 0);
    acc11 = __builtin_amdgcn_mfma_f32_16x16x32_bf16(a1, b1, acc11, 0, 0, 0);
  }

  float local = 0.f;
  int colA = lane & 15;
  int rbase = (lane >> 4) * 4;
  #pragma unroll
  for (int si = 0; si < 2; ++si) {
    #pragma unroll
    for (int sj = 0; sj < 2; ++sj) {
      f32x4 a = (si == 0) ? (sj == 0 ? acc00 : acc01) : (sj == 0 ? acc10 : acc11);
      #pragma unroll
      for (int r = 0; r < 4; ++r) {
        int i = i0 + si * 16 + rbase + r;
        int j = j0 + sj * 16 + colA;
        if (j < NCLS && i < j) {
          float d2 = sq[i] + sq[j] - 2.0f * a[r];
          float d = sqrtf(fmaxf(d2, 0.0f));
          local += fmaxf(1.0f - d, 0.0f);
        }
      }
    }
  }
  float tot = blockReduce1(local, smr);
  if (tid == 0) atomicAdd(&inter_partial[(bi * 16 + bj) & 255], tot);
}

// ---------------- K6: final combine ----------------

__global__ void final_kernel(const float* __restrict__ partials, float* __restrict__ out) {
  __shared__ float sm[8];
  int t = threadIdx.x;  // 256
  float c = partials[t] + partials[256 + t];
  float e = partials[512 + t];
  c = blockReduce1(c, sm);
  e = blockReduce1(e, sm);
  if (t == 0) {
    float intra = c * (1.0f / (float)BATCH);
    float inter = e / NPAIRS;
    out[0] = intra - 0.5f * inter;  // LAMBDA_INTRA=1, LAMBDA_INTER=0.5
  }
}

// ---------------- launch ----------------

extern "C" void kernel_launch(void* const* d_in, const int* in_sizes, int n_in,
                              void* d_out, int out_size, void* d_ws, size_t ws_size,
                              hipStream_t stream) {
  const float* features     = (const float*)d_in[0];
  const float* features_adv = (const float*)d_in[1];
  const float* centers      = (const float*)d_in[2];
  const int*   labels       = (const int*)d_in[3];
  float* out = (float*)d_out;

  // ws layout: centers_bf[1024*1024 u16] | sqn[1000 f] | invn[8192 f] |
  //            partials[768 f] | counts[1000 i] | offsets[1000 i] | rows_sorted[8192 i]
  unsigned short* centers_bf = (unsigned short*)d_ws;
  float* sqn = (float*)(centers_bf + (size_t)NPAD * DIM);
  float* invn = sqn + NCLS;
  float* partials = invn + BATCH;
  int* counts = (int*)(partials + 768);
  int* offsets = counts + NCLS;
  int* rows_sorted = offsets + NCLS;

  hipLaunchKernelGGL(norms_kernel, dim3(BATCH / 4), dim3(256), 0, stream,
                     features, invn);
  hipLaunchKernelGGL(hist_scan_scatter_kernel, dim3(1), dim3(1024), 0, stream, labels,
                     counts, offsets, rows_sorted, partials);
  hipLaunchKernelGGL(update_centers_kernel, dim3(NPAD), dim3(256), 0, stream, features,
                     centers, counts, offsets, rows_sorted, invn, centers_bf, sqn);
  hipLaunchKernelGGL(intra_kernel, dim3(BATCH / 4), dim3(256), 0, stream, features,
                     features_adv, centers_bf, labels, invn, partials);
  hipLaunchKernelGGL(inter_mfma_kernel, dim3(16, 16), dim3(256), 0, stream, centers_bf,
                     sqn, partials + 512);
  hipLaunchKernelGGL(final_kernel, dim3(1), dim3(256), 0, stream, partials, out);
}